// Round 19
// baseline (134.094 us; speedup 1.0000x reference)
//
#include <hip/hip_runtime.h>

#define F_DIM 256
#define H 5
#define C 7
#define PAD 8

#define PART_SH 9
#define PART_NODES 512
#define PCAP 20480
#define TILE 8192
#define EPT 8           // TILE / 1024
#define NPMAX 256
#define GSTRIDE 16      // gcur padded: one counter per 64B line
#define CSR_ROUNDS 20   // PCAP / 1024

// Partition one 8192-edge tile by dst>>9 into partition-major parr.
// 1024 threads (16 waves), wave-private counters, register-cached
// single-atomic-pass, line-padded gcur, per-wave segment-walk flush.
__global__ __launch_bounds__(1024) void k_part(
        const int* __restrict__ src, const int* __restrict__ dst,
        int* __restrict__ gcur, unsigned int* __restrict__ parr, int E, int np) {
    __shared__ unsigned int s_out[TILE];      // 32 KB
    __shared__ int s_wcur[16][NPMAX];         // 16 KB
    __shared__ int s_hist[NPMAX];
    __shared__ int s_excl[NPMAX];
    __shared__ int s_gbase[NPMAX];

    const int t = threadIdx.x;
    const int w = t >> 6;
    const int lane = t & 63;
    const int t0 = blockIdx.x * TILE;

    for (int i = t; i < 16 * NPMAX; i += 1024) ((int*)s_wcur)[i] = 0;
    __syncthreads();

    unsigned int pair[EPT];
    unsigned int meta[EPT];                   // (rank<<8) | p, ~0u = invalid
#pragma unroll
    for (int k = 0; k < EPT; ++k) {
        int e = t0 + k * 1024 + t;
        if (e < E) {
            int d = dst[e];
            int s = src[e];
            int p = d >> PART_SH;
            pair[k] = ((unsigned)s << PART_SH) | (unsigned)(d & (PART_NODES - 1));
            int rk = atomicAdd(&s_wcur[w][p], 1);
            meta[k] = ((unsigned)rk << 8) | (unsigned)p;
        } else {
            meta[k] = 0xFFFFFFFFu;
        }
    }
    __syncthreads();
    if (t < NPMAX) {
        int sum = 0;
#pragma unroll
        for (int ww = 0; ww < 16; ++ww) sum += s_wcur[ww][t];
        s_hist[t] = sum;
    }
    __syncthreads();
    if (t < 64) {
        int base = t * 4;
        int loc[4]; int tot = 0;
#pragma unroll
        for (int k = 0; k < 4; ++k) { loc[k] = tot; tot += s_hist[base + k]; }
        int incl = tot;
#pragma unroll
        for (int off = 1; off < 64; off <<= 1) {
            int u = __shfl_up(incl, off, 64);
            if (t >= off) incl += u;
        }
        int excl = incl - tot;
#pragma unroll
        for (int k = 0; k < 4; ++k) s_excl[base + k] = excl + loc[k];
    }
    __syncthreads();
    if (t < NPMAX) {
        int run = s_excl[t];
#pragma unroll
        for (int ww = 0; ww < 16; ++ww) { int c = s_wcur[ww][t]; s_wcur[ww][t] = run; run += c; }
        int cnt = s_hist[t];
        s_gbase[t] = (cnt > 0) ? atomicAdd(&gcur[t * GSTRIDE], cnt) : 0;
    }
    __syncthreads();
#pragma unroll
    for (int k = 0; k < EPT; ++k) {
        if (meta[k] != 0xFFFFFFFFu) {
            int p = meta[k] & 255;
            int rk = meta[k] >> 8;
            int pos = s_wcur[w][p] + rk;
            s_out[pos] = pair[k];
        }
    }
    __syncthreads();
    // per-wave segment-walk flush: wave w copies partitions w, w+16, ...
    for (int p = w; p < np; p += 16) {
        int e0 = s_excl[p];
        int e1 = s_excl[p + 1];
        int gb = s_gbase[p];
        for (int i = e0 + lane; i < e1; i += 64) {
            int gpos = gb + (i - e0);
            if (gpos < PCAP)
                parr[(size_t)p * PCAP + gpos] = s_out[i];
        }
    }
}

// hw1 = x @ W1, transposed: one thread per row, W1 scalarized (s_load).
__global__ __launch_bounds__(256) void k_xw1(const float* __restrict__ x,
                                             const float* __restrict__ W1,
                                             float* __restrict__ hw1, int n) {
    int row = blockIdx.x * 256 + threadIdx.x;
    if (row >= n) return;
    const float4* xp = (const float4*)(x + (size_t)row * F_DIM);
    float acc[H] = {0.f, 0.f, 0.f, 0.f, 0.f};
#pragma unroll 8
    for (int f4 = 0; f4 < F_DIM / 4; ++f4) {
        float4 v = xp[f4];
        const float* wp = W1 + f4 * 4 * H;   // lane-uniform -> scalar loads
#pragma unroll
        for (int c = 0; c < H; ++c)
            acc[c] += v.x * wp[c] + v.y * wp[H + c] + v.z * wp[2 * H + c] + v.w * wp[3 * H + c];
    }
    float* o = hw1 + (size_t)row * PAD;
    *reinterpret_cast<float4*>(o) = make_float4(acc[0], acc[1], acc[2], acc[3]);
    o[4] = acc[4];
}

// Per-partition CSR build (1024 threads, register-cached two-pass) + epilogue:
// dis, rpd, and hw1s = hw1 * dis[node].
__global__ __launch_bounds__(1024) void k_csr(
        const int* __restrict__ gcur, const unsigned int* __restrict__ parr,
        int* __restrict__ sorted, int2* __restrict__ rpd, float* __restrict__ dis,
        const float* __restrict__ hw1, float* __restrict__ hw1s, int n) {
    __shared__ int s_cnt[PART_NODES];
    __shared__ int s_excl[PART_NODES];
    const int p = blockIdx.x;
    const int t = threadIdx.x;
    int m = gcur[p * GSTRIDE]; if (m > PCAP) m = PCAP;
    const unsigned int* pp = parr + (size_t)p * PCAP;

    if (t < PART_NODES) s_cnt[t] = 0;
    __syncthreads();

    unsigned int pr[CSR_ROUNDS];
    int rk[CSR_ROUNDS];
#pragma unroll
    for (int k = 0; k < CSR_ROUNDS; ++k) {
        int i = k * 1024 + t;
        if (i < m) {
            pr[k] = pp[i];
            rk[k] = atomicAdd(&s_cnt[pr[k] & (PART_NODES - 1)], 1);
        }
    }
    __syncthreads();
    if (t < 64) {
        int base = t * 8;
        int loc[8]; int tot = 0;
#pragma unroll
        for (int k = 0; k < 8; ++k) { loc[k] = tot; tot += s_cnt[base + k]; }
        int incl = tot;
#pragma unroll
        for (int off = 1; off < 64; off <<= 1) {
            int u = __shfl_up(incl, off, 64);
            if (t >= off) incl += u;
        }
        int excl = incl - tot;
#pragma unroll
        for (int k = 0; k < 8; ++k) s_excl[base + k] = excl + loc[k];
    }
    __syncthreads();
    if (t < PART_NODES) {
        int node = p * PART_NODES + t;
        if (node < n) {
            int dg = s_cnt[t];
            rpd[node] = make_int2(p * PCAP + s_excl[t], dg);
            float di = rsqrtf((float)dg + 1.0f);
            dis[node] = di;
            const float* hp = hw1 + (size_t)node * PAD;
            float4 a = *(const float4*)hp;
            float h4 = hp[4];
            float* os = hw1s + (size_t)node * PAD;
            *reinterpret_cast<float4*>(os) = make_float4(a.x * di, a.y * di, a.z * di, a.w * di);
            os[4] = h4 * di;
        }
    }
#pragma unroll
    for (int k = 0; k < CSR_ROUNDS; ++k) {
        int i = k * 1024 + t;
        if (i < m) {
            int dloc = pr[k] & (PART_NODES - 1);
            sorted[(size_t)p * PCAP + s_excl[dloc] + rk[k]] = (int)(pr[k] >> PART_SH);
        }
    }
}

// Gather-aggregate (CSR) + fused epilogue. hin pre-scaled by dis[src].
// 4 lanes per node; 32-chunk (8 gathers in flight) then 16/8/4 tails.
template<int OUTD, int OSTRIDE, bool ADD_B3, bool SCALE_OUT>
__global__ __launch_bounds__(256) void k_layer(
        const int* __restrict__ sorted, const int2* __restrict__ rpd,
        const float* __restrict__ dis,
        const float* __restrict__ hin, const float* __restrict__ bn,
        const float* __restrict__ Wnext, const float* __restrict__ b3,
        float* __restrict__ outp, int n) {
    int tid = blockIdx.x * blockDim.x + threadIdx.x;
    int node = tid >> 2, sub = tid & 3;
    if (node >= n) return;
    int2 rd = rpd[node];
    int deg = rd.y;
    const int* bp = sorted + rd.x;

    float acc[H] = {0.f, 0.f, 0.f, 0.f, 0.f};
    int j = sub;
    for (; j + 32 <= deg; j += 32) {
        int s0 = bp[j], s1 = bp[j + 4], s2 = bp[j + 8], s3 = bp[j + 12];
        int s4 = bp[j + 16], s5 = bp[j + 20], s6 = bp[j + 24], s7 = bp[j + 28];
        const float4* h0 = (const float4*)(hin + (size_t)s0 * PAD);
        const float4* h1 = (const float4*)(hin + (size_t)s1 * PAD);
        const float4* h2 = (const float4*)(hin + (size_t)s2 * PAD);
        const float4* h3 = (const float4*)(hin + (size_t)s3 * PAD);
        const float4* h4 = (const float4*)(hin + (size_t)s4 * PAD);
        const float4* h5 = (const float4*)(hin + (size_t)s5 * PAD);
        const float4* h6 = (const float4*)(hin + (size_t)s6 * PAD);
        const float4* h7 = (const float4*)(hin + (size_t)s7 * PAD);
        float4 a0 = h0[0], e0 = h0[1], a1 = h1[0], e1 = h1[1];
        float4 a2 = h2[0], e2 = h2[1], a3 = h3[0], e3 = h3[1];
        float4 a4 = h4[0], e4 = h4[1], a5 = h5[0], e5 = h5[1];
        float4 a6 = h6[0], e6 = h6[1], a7 = h7[0], e7 = h7[1];
        acc[0] += (a0.x + a1.x + a2.x + a3.x) + (a4.x + a5.x + a6.x + a7.x);
        acc[1] += (a0.y + a1.y + a2.y + a3.y) + (a4.y + a5.y + a6.y + a7.y);
        acc[2] += (a0.z + a1.z + a2.z + a3.z) + (a4.z + a5.z + a6.z + a7.z);
        acc[3] += (a0.w + a1.w + a2.w + a3.w) + (a4.w + a5.w + a6.w + a7.w);
        acc[4] += (e0.x + e1.x + e2.x + e3.x) + (e4.x + e5.x + e6.x + e7.x);
    }
    for (; j + 16 <= deg; j += 16) {
        int s0 = bp[j], s1 = bp[j + 4], s2 = bp[j + 8], s3 = bp[j + 12];
        const float4* h0 = (const float4*)(hin + (size_t)s0 * PAD);
        const float4* h1 = (const float4*)(hin + (size_t)s1 * PAD);
        const float4* h2 = (const float4*)(hin + (size_t)s2 * PAD);
        const float4* h3 = (const float4*)(hin + (size_t)s3 * PAD);
        float4 a0 = h0[0], e0 = h0[1], a1 = h1[0], e1 = h1[1];
        float4 a2 = h2[0], e2 = h2[1], a3 = h3[0], e3 = h3[1];
        acc[0] += a0.x + a1.x + a2.x + a3.x;
        acc[1] += a0.y + a1.y + a2.y + a3.y;
        acc[2] += a0.z + a1.z + a2.z + a3.z;
        acc[3] += a0.w + a1.w + a2.w + a3.w;
        acc[4] += e0.x + e1.x + e2.x + e3.x;
    }
    for (; j + 8 <= deg; j += 8) {
        int s0 = bp[j], s1 = bp[j + 4];
        const float4* h0 = (const float4*)(hin + (size_t)s0 * PAD);
        const float4* h1 = (const float4*)(hin + (size_t)s1 * PAD);
        float4 a0 = h0[0], e0 = h0[1], a1 = h1[0], e1 = h1[1];
        acc[0] += a0.x + a1.x;
        acc[1] += a0.y + a1.y;
        acc[2] += a0.z + a1.z;
        acc[3] += a0.w + a1.w;
        acc[4] += e0.x + e1.x;
    }
    for (; j < deg; j += 4) {
        int s0 = bp[j];
        const float4* h0 = (const float4*)(hin + (size_t)s0 * PAD);
        float4 a0 = h0[0], e0 = h0[1];
        acc[0] += a0.x;
        acc[1] += a0.y;
        acc[2] += a0.z;
        acc[3] += a0.w;
        acc[4] += e0.x;
    }
#pragma unroll
    for (int c = 0; c < H; ++c) {
        acc[c] += __shfl_xor(acc[c], 1, 64);
        acc[c] += __shfl_xor(acc[c], 2, 64);
    }
    if (sub != 0) return;

    float di = dis[node];
    const float4* hp4 = (const float4*)(hin + (size_t)node * PAD);
    float4 ha = hp4[0];
    float h4 = hin[(size_t)node * PAD + 4];
    float hself[H] = {ha.x, ha.y, ha.z, ha.w, h4};
    float tt[H];
#pragma unroll
    for (int c = 0; c < H; ++c) {
        float v = (acc[c] + hself[c]) * di + bn[c];
        tt[c] = v > 0.f ? v : 0.f;
    }
    float* op = outp + (size_t)node * OSTRIDE;
#pragma unroll
    for (int c2 = 0; c2 < OUTD; ++c2) {
        float a = ADD_B3 ? b3[c2] : 0.f;
#pragma unroll
        for (int c = 0; c < H; ++c) a += tt[c] * Wnext[c * OUTD + c2];
        op[c2] = SCALE_OUT ? a * di : a;
    }
}

extern "C" void kernel_launch(void* const* d_in, const int* in_sizes, int n_in,
                              void* d_out, int out_size, void* d_ws, size_t ws_size,
                              hipStream_t stream) {
    const float* x  = (const float*)d_in[0];
    const int*   ei = (const int*)d_in[1];
    const float* W1 = (const float*)d_in[2];
    const float* b1 = (const float*)d_in[3];
    const float* W2 = (const float*)d_in[4];
    const float* b2 = (const float*)d_in[5];
    const float* W3 = (const float*)d_in[6];
    const float* b3 = (const float*)d_in[7];
    float* out = (float*)d_out;

    const int n = in_sizes[0] / F_DIM;
    const int E = in_sizes[1] / 2;
    const int* src = ei;
    const int* dst = ei + E;
    const int np = (n + PART_NODES - 1) / PART_NODES;

    char* ws = (char*)d_ws;
    size_t off = 0;
    int* gcur = (int*)(ws + off);                   off += (size_t)NPMAX * GSTRIDE * 4;
    unsigned int* parr = (unsigned int*)(ws + off); off += (size_t)np * PCAP * 4;
    int* sorted = (int*)(ws + off);                 off += (size_t)np * PCAP * 4;
    int2* rpd = (int2*)(ws + off);                  off += (size_t)n * 8;
    float* dis = (float*)(ws + off);                off += (size_t)n * 4;
    float* hw1 = (float*)(ws + off);                off += (size_t)n * PAD * 4;
    float* hw1s = (float*)(ws + off);               off += (size_t)n * PAD * 4;
    float* hw2 = (float*)(ws + off);                off += (size_t)n * PAD * 4;

    const int nbp = (E + TILE - 1) / TILE;
    const int nbx = (n + 255) / 256;
    const int nb4 = (4 * n + 255) / 256;

    hipMemsetAsync(gcur, 0, (size_t)NPMAX * GSTRIDE * sizeof(int), stream);
    k_part<<<nbp, 1024, 0, stream>>>(src, dst, gcur, parr, E, np);
    k_xw1<<<nbx, 256, 0, stream>>>(x, W1, hw1, n);
    k_csr<<<np, 1024, 0, stream>>>(gcur, parr, sorted, rpd, dis, hw1, hw1s, n);
    // layer1: hw1s pre-scaled by dis; write (t@W2)*dis[node] into hw2
    k_layer<H, PAD, false, true><<<nb4, 256, 0, stream>>>(
        sorted, rpd, dis, hw1s, b1, W2, nullptr, hw2, n);
    // layer2: hw2 carries dis factor; add b3, write logits
    k_layer<C, C, true, false><<<nb4, 256, 0, stream>>>(
        sorted, rpd, dis, hw2, b2, W3, b3, out, n);
}

// Round 20
// 120.817 us; speedup vs baseline: 1.1099x; 1.1099x over previous
//
#include <hip/hip_runtime.h>

#define F_DIM 256
#define H 5
#define C 7
#define PAD 8

#define PART_SH 9
#define PART_NODES 512
#define PCAP 20480
#define TILE 8192
#define EPT 16          // TILE / 512
#define NPMAX 256
#define GSTRIDE 16      // gcur padded: one counter per 64B line
#define CSR_ROUNDS 20   // PCAP / 1024

// Fused: blocks [0,nbp) partition one 8192-edge tile by dst>>9 into
// partition-major parr; blocks [nbp,..) compute hw1 = x @ W1 (thread-per-row).
// Flush is per-wave segment-walk: no per-edge partition tag,
// LDS reads conflict-free, global writes fully coalesced.
__global__ __launch_bounds__(512) void k_pxw(
        const int* __restrict__ src, const int* __restrict__ dst,
        int* __restrict__ gcur, unsigned int* __restrict__ parr, int E, int nbp, int np,
        const float* __restrict__ x, const float* __restrict__ W1,
        float* __restrict__ hw1, int n) {
    const int t = threadIdx.x;
    if ((int)blockIdx.x < nbp) {
        __shared__ unsigned int s_out[TILE];      // 32 KB
        __shared__ int s_wcur[8][NPMAX];          // 8 KB
        __shared__ int s_hist[NPMAX];
        __shared__ int s_excl[NPMAX];
        __shared__ int s_gbase[NPMAX];

        const int w = t >> 6;
        const int lane = t & 63;
        const int t0 = blockIdx.x * TILE;

        for (int i = t; i < 8 * NPMAX; i += 512) ((int*)s_wcur)[i] = 0;
        __syncthreads();

        unsigned int pair[EPT];
        unsigned int meta[EPT];                   // (rank<<8) | p, ~0u = invalid
#pragma unroll
        for (int k = 0; k < EPT; ++k) {
            int e = t0 + k * 512 + t;
            if (e < E) {
                int d = dst[e];
                int s = src[e];
                int p = d >> PART_SH;
                pair[k] = ((unsigned)s << PART_SH) | (unsigned)(d & (PART_NODES - 1));
                int rk = atomicAdd(&s_wcur[w][p], 1);
                meta[k] = ((unsigned)rk << 8) | (unsigned)p;
            } else {
                meta[k] = 0xFFFFFFFFu;
            }
        }
        __syncthreads();
        if (t < NPMAX) {
            int sum = 0;
#pragma unroll
            for (int ww = 0; ww < 8; ++ww) sum += s_wcur[ww][t];
            s_hist[t] = sum;
        }
        __syncthreads();
        if (t < 64) {
            int base = t * 4;
            int loc[4]; int tot = 0;
#pragma unroll
            for (int k = 0; k < 4; ++k) { loc[k] = tot; tot += s_hist[base + k]; }
            int incl = tot;
#pragma unroll
            for (int off = 1; off < 64; off <<= 1) {
                int u = __shfl_up(incl, off, 64);
                if (t >= off) incl += u;
            }
            int excl = incl - tot;
#pragma unroll
            for (int k = 0; k < 4; ++k) s_excl[base + k] = excl + loc[k];
        }
        __syncthreads();
        if (t < NPMAX) {
            int run = s_excl[t];
#pragma unroll
            for (int ww = 0; ww < 8; ++ww) { int c = s_wcur[ww][t]; s_wcur[ww][t] = run; run += c; }
            int cnt = s_hist[t];
            s_gbase[t] = (cnt > 0) ? atomicAdd(&gcur[t * GSTRIDE], cnt) : 0;
        }
        __syncthreads();
#pragma unroll
        for (int k = 0; k < EPT; ++k) {
            if (meta[k] != 0xFFFFFFFFu) {
                int p = meta[k] & 255;
                int rk = meta[k] >> 8;
                int pos = s_wcur[w][p] + rk;
                s_out[pos] = pair[k];
            }
        }
        __syncthreads();
        // per-wave segment-walk flush: wave w copies partitions w, w+8, ...
        for (int p = w; p < np; p += 8) {
            int e0 = s_excl[p];
            int e1 = s_excl[p + 1];
            int gb = s_gbase[p];
            for (int i = e0 + lane; i < e1; i += 64) {
                int gpos = gb + (i - e0);
                if (gpos < PCAP)
                    parr[(size_t)p * PCAP + gpos] = s_out[i];
            }
        }
    } else {
        int row = ((int)blockIdx.x - nbp) * 512 + t;
        if (row >= n) return;
        const float4* xp = (const float4*)(x + (size_t)row * F_DIM);
        float acc[H] = {0.f, 0.f, 0.f, 0.f, 0.f};
#pragma unroll 8
        for (int f4 = 0; f4 < F_DIM / 4; ++f4) {
            float4 v = xp[f4];
            const float* wp = W1 + f4 * 4 * H;   // lane-uniform -> scalar loads
#pragma unroll
            for (int c = 0; c < H; ++c)
                acc[c] += v.x * wp[c] + v.y * wp[H + c] + v.z * wp[2 * H + c] + v.w * wp[3 * H + c];
        }
        float* o = hw1 + (size_t)row * PAD;
        *reinterpret_cast<float4*>(o) = make_float4(acc[0], acc[1], acc[2], acc[3]);
        o[4] = acc[4];
    }
}

// Per-partition CSR build (1024 threads, register-cached two-pass) + epilogue:
// dis, rpd, and hw1s = hw1 * dis[node].
__global__ __launch_bounds__(1024) void k_csr(
        const int* __restrict__ gcur, const unsigned int* __restrict__ parr,
        int* __restrict__ sorted, int2* __restrict__ rpd, float* __restrict__ dis,
        const float* __restrict__ hw1, float* __restrict__ hw1s, int n) {
    __shared__ int s_cnt[PART_NODES];
    __shared__ int s_excl[PART_NODES];
    const int p = blockIdx.x;
    const int t = threadIdx.x;
    int m = gcur[p * GSTRIDE]; if (m > PCAP) m = PCAP;
    const unsigned int* pp = parr + (size_t)p * PCAP;

    if (t < PART_NODES) s_cnt[t] = 0;
    __syncthreads();

    unsigned int pr[CSR_ROUNDS];
    int rk[CSR_ROUNDS];
#pragma unroll
    for (int k = 0; k < CSR_ROUNDS; ++k) {
        int i = k * 1024 + t;
        if (i < m) {
            pr[k] = pp[i];
            rk[k] = atomicAdd(&s_cnt[pr[k] & (PART_NODES - 1)], 1);
        }
    }
    __syncthreads();
    if (t < 64) {
        int base = t * 8;
        int loc[8]; int tot = 0;
#pragma unroll
        for (int k = 0; k < 8; ++k) { loc[k] = tot; tot += s_cnt[base + k]; }
        int incl = tot;
#pragma unroll
        for (int off = 1; off < 64; off <<= 1) {
            int u = __shfl_up(incl, off, 64);
            if (t >= off) incl += u;
        }
        int excl = incl - tot;
#pragma unroll
        for (int k = 0; k < 8; ++k) s_excl[base + k] = excl + loc[k];
    }
    __syncthreads();
    if (t < PART_NODES) {
        int node = p * PART_NODES + t;
        if (node < n) {
            int dg = s_cnt[t];
            rpd[node] = make_int2(p * PCAP + s_excl[t], dg);
            float di = rsqrtf((float)dg + 1.0f);
            dis[node] = di;
            const float* hp = hw1 + (size_t)node * PAD;
            float4 a = *(const float4*)hp;
            float h4 = hp[4];
            float* os = hw1s + (size_t)node * PAD;
            *reinterpret_cast<float4*>(os) = make_float4(a.x * di, a.y * di, a.z * di, a.w * di);
            os[4] = h4 * di;
        }
    }
#pragma unroll
    for (int k = 0; k < CSR_ROUNDS; ++k) {
        int i = k * 1024 + t;
        if (i < m) {
            int dloc = pr[k] & (PART_NODES - 1);
            sorted[(size_t)p * PCAP + s_excl[dloc] + rk[k]] = (int)(pr[k] >> PART_SH);
        }
    }
}

// Gather-aggregate (CSR) + fused epilogue. hin pre-scaled by dis[src].
// 4 lanes per node; 32-chunk (8 gathers in flight) then 16/8/4 tails.
template<int OUTD, int OSTRIDE, bool ADD_B3, bool SCALE_OUT>
__global__ __launch_bounds__(256) void k_layer(
        const int* __restrict__ sorted, const int2* __restrict__ rpd,
        const float* __restrict__ dis,
        const float* __restrict__ hin, const float* __restrict__ bn,
        const float* __restrict__ Wnext, const float* __restrict__ b3,
        float* __restrict__ outp, int n) {
    int tid = blockIdx.x * blockDim.x + threadIdx.x;
    int node = tid >> 2, sub = tid & 3;
    if (node >= n) return;
    int2 rd = rpd[node];
    int deg = rd.y;
    const int* bp = sorted + rd.x;

    float acc[H] = {0.f, 0.f, 0.f, 0.f, 0.f};
    int j = sub;
    for (; j + 32 <= deg; j += 32) {
        int s0 = bp[j], s1 = bp[j + 4], s2 = bp[j + 8], s3 = bp[j + 12];
        int s4 = bp[j + 16], s5 = bp[j + 20], s6 = bp[j + 24], s7 = bp[j + 28];
        const float4* h0 = (const float4*)(hin + (size_t)s0 * PAD);
        const float4* h1 = (const float4*)(hin + (size_t)s1 * PAD);
        const float4* h2 = (const float4*)(hin + (size_t)s2 * PAD);
        const float4* h3 = (const float4*)(hin + (size_t)s3 * PAD);
        const float4* h4 = (const float4*)(hin + (size_t)s4 * PAD);
        const float4* h5 = (const float4*)(hin + (size_t)s5 * PAD);
        const float4* h6 = (const float4*)(hin + (size_t)s6 * PAD);
        const float4* h7 = (const float4*)(hin + (size_t)s7 * PAD);
        float4 a0 = h0[0], e0 = h0[1], a1 = h1[0], e1 = h1[1];
        float4 a2 = h2[0], e2 = h2[1], a3 = h3[0], e3 = h3[1];
        float4 a4 = h4[0], e4 = h4[1], a5 = h5[0], e5 = h5[1];
        float4 a6 = h6[0], e6 = h6[1], a7 = h7[0], e7 = h7[1];
        acc[0] += (a0.x + a1.x + a2.x + a3.x) + (a4.x + a5.x + a6.x + a7.x);
        acc[1] += (a0.y + a1.y + a2.y + a3.y) + (a4.y + a5.y + a6.y + a7.y);
        acc[2] += (a0.z + a1.z + a2.z + a3.z) + (a4.z + a5.z + a6.z + a7.z);
        acc[3] += (a0.w + a1.w + a2.w + a3.w) + (a4.w + a5.w + a6.w + a7.w);
        acc[4] += (e0.x + e1.x + e2.x + e3.x) + (e4.x + e5.x + e6.x + e7.x);
    }
    for (; j + 16 <= deg; j += 16) {
        int s0 = bp[j], s1 = bp[j + 4], s2 = bp[j + 8], s3 = bp[j + 12];
        const float4* h0 = (const float4*)(hin + (size_t)s0 * PAD);
        const float4* h1 = (const float4*)(hin + (size_t)s1 * PAD);
        const float4* h2 = (const float4*)(hin + (size_t)s2 * PAD);
        const float4* h3 = (const float4*)(hin + (size_t)s3 * PAD);
        float4 a0 = h0[0], e0 = h0[1], a1 = h1[0], e1 = h1[1];
        float4 a2 = h2[0], e2 = h2[1], a3 = h3[0], e3 = h3[1];
        acc[0] += a0.x + a1.x + a2.x + a3.x;
        acc[1] += a0.y + a1.y + a2.y + a3.y;
        acc[2] += a0.z + a1.z + a2.z + a3.z;
        acc[3] += a0.w + a1.w + a2.w + a3.w;
        acc[4] += e0.x + e1.x + e2.x + e3.x;
    }
    for (; j + 8 <= deg; j += 8) {
        int s0 = bp[j], s1 = bp[j + 4];
        const float4* h0 = (const float4*)(hin + (size_t)s0 * PAD);
        const float4* h1 = (const float4*)(hin + (size_t)s1 * PAD);
        float4 a0 = h0[0], e0 = h0[1], a1 = h1[0], e1 = h1[1];
        acc[0] += a0.x + a1.x;
        acc[1] += a0.y + a1.y;
        acc[2] += a0.z + a1.z;
        acc[3] += a0.w + a1.w;
        acc[4] += e0.x + e1.x;
    }
    for (; j < deg; j += 4) {
        int s0 = bp[j];
        const float4* h0 = (const float4*)(hin + (size_t)s0 * PAD);
        float4 a0 = h0[0], e0 = h0[1];
        acc[0] += a0.x;
        acc[1] += a0.y;
        acc[2] += a0.z;
        acc[3] += a0.w;
        acc[4] += e0.x;
    }
#pragma unroll
    for (int c = 0; c < H; ++c) {
        acc[c] += __shfl_xor(acc[c], 1, 64);
        acc[c] += __shfl_xor(acc[c], 2, 64);
    }
    if (sub != 0) return;

    float di = dis[node];
    const float4* hp4 = (const float4*)(hin + (size_t)node * PAD);
    float4 ha = hp4[0];
    float h4 = hin[(size_t)node * PAD + 4];
    float hself[H] = {ha.x, ha.y, ha.z, ha.w, h4};
    float tt[H];
#pragma unroll
    for (int c = 0; c < H; ++c) {
        float v = (acc[c] + hself[c]) * di + bn[c];
        tt[c] = v > 0.f ? v : 0.f;
    }
    float* op = outp + (size_t)node * OSTRIDE;
#pragma unroll
    for (int c2 = 0; c2 < OUTD; ++c2) {
        float a = ADD_B3 ? b3[c2] : 0.f;
#pragma unroll
        for (int c = 0; c < H; ++c) a += tt[c] * Wnext[c * OUTD + c2];
        op[c2] = SCALE_OUT ? a * di : a;
    }
}

extern "C" void kernel_launch(void* const* d_in, const int* in_sizes, int n_in,
                              void* d_out, int out_size, void* d_ws, size_t ws_size,
                              hipStream_t stream) {
    const float* x  = (const float*)d_in[0];
    const int*   ei = (const int*)d_in[1];
    const float* W1 = (const float*)d_in[2];
    const float* b1 = (const float*)d_in[3];
    const float* W2 = (const float*)d_in[4];
    const float* b2 = (const float*)d_in[5];
    const float* W3 = (const float*)d_in[6];
    const float* b3 = (const float*)d_in[7];
    float* out = (float*)d_out;

    const int n = in_sizes[0] / F_DIM;
    const int E = in_sizes[1] / 2;
    const int* src = ei;
    const int* dst = ei + E;
    const int np = (n + PART_NODES - 1) / PART_NODES;

    char* ws = (char*)d_ws;
    size_t off = 0;
    int* gcur = (int*)(ws + off);                   off += (size_t)NPMAX * GSTRIDE * 4;
    unsigned int* parr = (unsigned int*)(ws + off); off += (size_t)np * PCAP * 4;
    int* sorted = (int*)(ws + off);                 off += (size_t)np * PCAP * 4;
    int2* rpd = (int2*)(ws + off);                  off += (size_t)n * 8;
    float* dis = (float*)(ws + off);                off += (size_t)n * 4;
    float* hw1 = (float*)(ws + off);                off += (size_t)n * PAD * 4;
    float* hw1s = (float*)(ws + off);               off += (size_t)n * PAD * 4;
    float* hw2 = (float*)(ws + off);                off += (size_t)n * PAD * 4;

    const int nbp = (E + TILE - 1) / TILE;
    const int nbx = (n + 511) / 512;
    const int nb4 = (4 * n + 255) / 256;

    hipMemsetAsync(gcur, 0, (size_t)NPMAX * GSTRIDE * sizeof(int), stream);
    k_pxw<<<nbp + nbx, 512, 0, stream>>>(src, dst, gcur, parr, E, nbp, np, x, W1, hw1, n);
    k_csr<<<np, 1024, 0, stream>>>(gcur, parr, sorted, rpd, dis, hw1, hw1s, n);
    // layer1: hw1s pre-scaled by dis; write (t@W2)*dis[node] into hw2
    k_layer<H, PAD, false, true><<<nb4, 256, 0, stream>>>(
        sorted, rpd, dis, hw1s, b1, W2, nullptr, hw2, n);
    // layer2: hw2 carries dis factor; add b3, write logits
    k_layer<C, C, true, false><<<nb4, 256, 0, stream>>>(
        sorted, rpd, dis, hw2, b2, W3, b3, out, n);
}